// Round 5
// baseline (375.952 us; speedup 1.0000x reference)
//
#include <hip/hip_runtime.h>

typedef unsigned short u16;
typedef unsigned int u32;
typedef __attribute__((ext_vector_type(8))) short short8;
typedef __attribute__((ext_vector_type(4))) float floatx4;

#define GLOAD_LDS16(gp, lp)                                                              \
  __builtin_amdgcn_global_load_lds((const __attribute__((address_space(1))) void*)(gp),  \
                                   (__attribute__((address_space(3))) void*)(lp), 16, 0, 0)

__device__ __forceinline__ u16 f2bf(float f) {
  u32 u = __float_as_uint(f);
  u += 0x7fffu + ((u >> 16) & 1u);   // round-to-nearest-even
  return (u16)(u >> 16);
}

__device__ __forceinline__ void bf8_to_f(const u16* p, float* o) {
  const uint4 v = *(const uint4*)p;
  const u32 a[4] = {v.x, v.y, v.z, v.w};
#pragma unroll
  for (int i = 0; i < 4; i++) {
    o[2 * i]     = __uint_as_float(a[i] << 16);
    o[2 * i + 1] = __uint_as_float(a[i] & 0xffff0000u);
  }
}

// ------ prep A: W transpose+cvt only (round-0 logic), 9216 blocks -----------------
__global__ __launch_bounds__(256) void prep_w_kernel(
    const float* __restrict__ W1a, const float* __restrict__ W2a,
    const float* __restrict__ W1b, const float* __restrict__ W2b,
    u16* __restrict__ T1a, u16* __restrict__ T2a,
    u16* __restrict__ T1b, u16* __restrict__ T2b) {
  __shared__ float tile[64][65];
  const int id = blockIdx.x;
  const int t = threadIdx.x;

  const int tsel = id / 2304;
  const int rem = id % 2304;
  const int e = rem >> 7;
  const int t128 = rem & 127;
  const int K = (tsel & 1) ? 1024 : 512;
  const int N = (tsel & 1) ? 512 : 1024;
  const int kt = (tsel & 1) ? (t128 & 15) : (t128 & 7);
  const int nt = (tsel & 1) ? (t128 >> 4) : (t128 >> 3);
  const int k0 = kt * 64, n0 = nt * 64;
  const float* W = (tsel == 0) ? W1a : (tsel == 1) ? W2a : (tsel == 2) ? W1b : W2b;
  u16* WT = (tsel == 0) ? T1a : (tsel == 1) ? T2a : (tsel == 2) ? T1b : T2b;

  const float* Wp = W + ((size_t)e * K + k0) * N + n0;
  const int r = t >> 4;          // 0..15
  const int c = (t & 15) << 2;   // 0..60
#pragma unroll
  for (int p = 0; p < 4; p++) {
    const int row = r + p * 16;
    const float4 v = *(const float4*)(Wp + (size_t)row * N + c);
    tile[row][c + 0] = v.x; tile[row][c + 1] = v.y;
    tile[row][c + 2] = v.z; tile[row][c + 3] = v.w;
  }
  __syncthreads();
  u16* WTp = WT + ((size_t)e * N + n0) * K + k0;
#pragma unroll
  for (int p = 0; p < 4; p++) {
    const int row = r + p * 16;  // n index within tile
    u32 lo = (u32)f2bf(tile[c + 0][row]) | ((u32)f2bf(tile[c + 1][row]) << 16);
    u32 hi = (u32)f2bf(tile[c + 2][row]) | ((u32)f2bf(tile[c + 3][row]) << 16);
    *(uint2*)(WTp + (size_t)row * K + c) = make_uint2(lo, hi);
  }
}

// ------ prep B: Wg transpose (612 blocks) + x0 cvt (4608 blocks) ------------------
__global__ __launch_bounds__(256) void prep_misc_kernel(
    const float* __restrict__ Wg0, const float* __restrict__ Wg1,
    u16* __restrict__ WgT0, u16* __restrict__ WgT1,
    const float* __restrict__ x0, u16* __restrict__ x0bf) {
  const int id = blockIdx.x;
  const int t = threadIdx.x;
  if (id < 612) {
    int idx = id * 256 + t;
    const float* Wg = Wg0;
    u16* WgT = WgT0;
    if (idx >= 82944) { idx -= 82944; Wg = Wg1; WgT = WgT1; }
    const int d = idx & 511;
    const int r = idx >> 9;
    const int e = r % 18;
    const int m = r / 18;
    WgT[idx] = f2bf(Wg[((size_t)(m * 512 + d)) * 18 + e]);
  } else {
    const int i = (id - 612) * 256 + t;   // 4608*256 == 1179648 float4s exactly
    const float4 v = ((const float4*)x0)[i];
    u32 lo = (u32)f2bf(v.x) | ((u32)f2bf(v.y) << 16);
    u32 hi = (u32)f2bf(v.z) | ((u32)f2bf(v.w) << 16);
    ((uint2*)x0bf)[i] = make_uint2(lo, hi);
  }
}

// ---------------- gating body: wsm[b][m][18] = softmax(x[b,m,:]·Wg[m] + bg[m]) + add --
// bid in [0, 128*M); wave handles 2 batches; x bf16 [B][9][512]; WgT bf16 [M][18][512]
template <int M, int LAYER>
__device__ __forceinline__ void gating_body(
    int bid, const u16* __restrict__ xbf, const u16* __restrict__ WgT,
    const float* __restrict__ bg, const float* __restrict__ sew_task,
    const float* __restrict__ sew_shared, float* __restrict__ wsm) {
  const int lane = threadIdx.x & 63;
  const int wave = threadIdx.x >> 6;
  const int m = bid >> 7;
  const int b0 = (bid & 127) * 8 + wave * 2;

  float xa[8], xb[8];
  bf8_to_f(xbf + (size_t)b0 * 4608 + m * 512 + lane * 8, xa);
  bf8_to_f(xbf + (size_t)(b0 + 1) * 4608 + m * 512 + lane * 8, xb);

  float lg0[18], lg1[18];
#pragma unroll
  for (int e = 0; e < 18; e++) {
    float w[8];
    bf8_to_f(WgT + ((size_t)m * 18 + e) * 512 + lane * 8, w);
    float s0 = 0.f, s1 = 0.f;
#pragma unroll
    for (int i = 0; i < 8; i++) { s0 = fmaf(w[i], xa[i], s0); s1 = fmaf(w[i], xb[i], s1); }
#pragma unroll
    for (int off = 1; off < 64; off <<= 1) {
      s0 += __shfl_xor(s0, off, 64);
      s1 += __shfl_xor(s1, off, 64);
    }
    const float bgv = bg[m * 18 + e];
    lg0[e] = s0 + bgv;
    lg1[e] = s1 + bgv;
  }
  float mx0 = lg0[0], mx1 = lg1[0];
#pragma unroll
  for (int e = 1; e < 18; e++) { mx0 = fmaxf(mx0, lg0[e]); mx1 = fmaxf(mx1, lg1[e]); }
  float sum0 = 0.f, sum1 = 0.f;
#pragma unroll
  for (int e = 0; e < 18; e++) { sum0 += __expf(lg0[e] - mx0); sum1 += __expf(lg1[e] - mx1); }
  float my0 = lg0[0], my1 = lg1[0];
#pragma unroll
  for (int e = 1; e < 18; e++)
    if (lane == e) { my0 = lg0[e]; my1 = lg1[e]; }
  float w0 = __expf(my0 - mx0) / sum0;
  float w1 = __expf(my1 - mx1) / sum1;
  if ((lane >> 1) == m) {
    float add;
    if (M == 9 && m == 8) add = sew_shared[lane & 1];
    else                  add = sew_task[m * 4 + 2 * LAYER + (lane & 1)];
    w0 += add; w1 += add;
  }
  if (lane < 18) {
    wsm[((size_t)b0 * M + m) * 18 + lane] = w0;
    wsm[((size_t)(b0 + 1) * M + m) * 18 + lane] = w1;
  }
}

// ---------------- MFMA GEMM v3: BM=256 x BN=128 tiles (cache-BW fix) ------------------
// staging traffic = E*M*N*K*2B*(1/BM+1/BN): 302 MB -> 226 MB per GEMM.
// 4 waves; wave w owns rows [w*64, w*64+64) x all 128 cols; acc[4][8].
// blocks [0,G): GEMM, XCD-swizzled; blocks [G,...): gating.
template <bool RELU_BF16_OUT, int M, int LAYER, bool GATE>
__global__ __launch_bounds__(256, 2) void gemm_fused_kernel(
    const u16* __restrict__ A, const u16* __restrict__ BT,
    const float* __restrict__ bias, void* __restrict__ Cout,
    int lda, int a_shift, int a_mul, int ldc, int c_mul, int N, int K, int nshift, int G,
    const u16* __restrict__ WgT, const float* __restrict__ bg,
    const float* __restrict__ sewt, const float* __restrict__ sews,
    float* __restrict__ wsm) {
  if (GATE && (int)blockIdx.x >= G) {
    gating_body<M, LAYER>(blockIdx.x - G, A, WgT, bg, sewt, sews, wsm);
    return;
  }
  __shared__ __align__(16) u16 As[256 * 64];   // 32 KB
  __shared__ __align__(16) u16 Bs[128 * 64];   // 16 KB

  const int tid = threadIdx.x;
  const int lane = tid & 63;
  const int wave = tid >> 6;

  const int L = blockIdx.x;
  const int per_xcd = G >> 3;
  const int g = (L & 7) * per_xcd + (L >> 3);
  const int e = g >> nshift;
  const int wb = g & ((1 << nshift) - 1);
  const int mt = wb & 3;           // M = 1024 always -> 4 row tiles of 256 (share B)
  const int nt = wb >> 2;
  const int m0 = mt << 8, n0 = nt << 7;

  const u16* Aexp = A + (size_t)((e >> a_shift) * a_mul);
  const u16* Bexp = BT + (size_t)e * (size_t)N * (size_t)K;

  // staging: chunk = 1KB = 8 rows; lane l -> row c*8 + l/8, pre-swizzled col group
  const int colsw = (((lane & 7) ^ ((lane >> 3) & 7)) << 3);
  const u16* aptr[8];
  u16* lA[8];
  const u16* bptr[4];
  u16* lB[4];
#pragma unroll
  for (int i = 0; i < 8; i++) {
    const int cch = wave * 8 + i;             // 0..31 (256 rows)
    const int row = cch * 8 + (lane >> 3);
    aptr[i] = Aexp + (size_t)(m0 + row) * lda + colsw;
    lA[i] = As + cch * 512;
  }
#pragma unroll
  for (int i = 0; i < 4; i++) {
    const int cch = wave * 4 + i;             // 0..15 (128 rows)
    const int row = cch * 8 + (lane >> 3);
    bptr[i] = Bexp + (size_t)(n0 + row) * K + colsw;
    lB[i] = Bs + cch * 512;
  }

  floatx4 acc[4][8];
#pragma unroll
  for (int i = 0; i < 4; i++)
#pragma unroll
    for (int j = 0; j < 8; j++) acc[i][j] = (floatx4){0.f, 0.f, 0.f, 0.f};

  const int wm = wave << 6;
  const int r15 = lane & 15;
  const int quad = lane >> 4;

  int aoff[4], boff[8];
#pragma unroll
  for (int i = 0; i < 4; i++) {
    const int ra = wm + i * 16 + r15;
    aoff[i] = ra * 64 + ((quad ^ (ra & 7)) << 3);
  }
#pragma unroll
  for (int j = 0; j < 8; j++) {
    const int rb = j * 16 + r15;
    boff[j] = rb * 64 + ((quad ^ (rb & 7)) << 3);
  }

  for (int k0 = 0; k0 < K; k0 += 64) {
    __syncthreads();
#pragma unroll
    for (int i = 0; i < 8; i++) GLOAD_LDS16(aptr[i] + k0, lA[i]);
#pragma unroll
    for (int i = 0; i < 4; i++) GLOAD_LDS16(bptr[i] + k0, lB[i]);
    __syncthreads();
#pragma unroll
    for (int s = 0; s < 2; s++) {
      short8 af[4], bfr[8];
#pragma unroll
      for (int i = 0; i < 4; i++) af[i] = *(const short8*)(As + (aoff[i] ^ (s << 5)));
#pragma unroll
      for (int j = 0; j < 8; j++) bfr[j] = *(const short8*)(Bs + (boff[j] ^ (s << 5)));
      __builtin_amdgcn_s_setprio(1);
#pragma unroll
      for (int i = 0; i < 4; i++)
#pragma unroll
        for (int j = 0; j < 8; j++)
          acc[i][j] = __builtin_amdgcn_mfma_f32_16x16x32_bf16(af[i], bfr[j], acc[i][j], 0, 0, 0);
      __builtin_amdgcn_s_setprio(0);
    }
  }

  const int ccol0 = n0 + r15;
  const int crow0 = m0 + wm + quad * 4;
  float bv[8];
#pragma unroll
  for (int j = 0; j < 8; j++) bv[j] = bias[e * N + ccol0 + j * 16];

  if constexpr (RELU_BF16_OUT) {
    u16* Co = (u16*)Cout + (size_t)e * c_mul;
#pragma unroll
    for (int i = 0; i < 4; i++)
#pragma unroll
      for (int r = 0; r < 4; r++) {
        const size_t rowoff = (size_t)(crow0 + i * 16 + r) * ldc;
#pragma unroll
        for (int j = 0; j < 8; j++) {
          float v = acc[i][j][r] + bv[j];
          v = v > 0.f ? v : 0.f;
          Co[rowoff + ccol0 + j * 16] = f2bf(v);
        }
      }
  } else {
    float* Co = (float*)Cout + (size_t)e * c_mul;
#pragma unroll
    for (int i = 0; i < 4; i++)
#pragma unroll
      for (int r = 0; r < 4; r++) {
        const size_t rowoff = (size_t)(crow0 + i * 16 + r) * ldc;
#pragma unroll
        for (int j = 0; j < 8; j++) Co[rowoff + ccol0 + j * 16] = acc[i][j][r] + bv[j];
      }
  }
}

// ---------------- weighted sum: out[b][m][:] = sum_e wsm[b][m][e] * eo[b][e][:] -------
template <int M, bool BF16OUT>
__global__ __launch_bounds__(256) void wsum_kernel(
    const float* __restrict__ eo, const float* __restrict__ wsm,
    float* __restrict__ outf, u16* __restrict__ outb) {
  __shared__ float ws[2 * M * 18];
  const int t = threadIdx.x;
  const int b0 = blockIdx.x * 2;
  for (int i = t; i < 2 * M * 18; i += 256) ws[i] = wsm[(size_t)b0 * M * 18 + i];
  __syncthreads();
  const int lb = t >> 7;
  const int s = t & 127;
  const int b = b0 + lb;
  const float* eob = eo + (size_t)b * 9216 + s * 4;
  const float* wr = ws + lb * M * 18;

  float4 acc[M];
#pragma unroll
  for (int m = 0; m < M; m++) acc[m] = make_float4(0.f, 0.f, 0.f, 0.f);
#pragma unroll
  for (int e = 0; e < 18; e++) {
    const float4 v = *(const float4*)(eob + e * 512);
#pragma unroll
    for (int m = 0; m < M; m++) {
      const float w = wr[m * 18 + e];
      acc[m].x = fmaf(w, v.x, acc[m].x);
      acc[m].y = fmaf(w, v.y, acc[m].y);
      acc[m].z = fmaf(w, v.z, acc[m].z);
      acc[m].w = fmaf(w, v.w, acc[m].w);
    }
  }
  if constexpr (BF16OUT) {
    u16* ob = outb + (size_t)b * 4608 + s * 4;
#pragma unroll
    for (int m = 0; m < M; m++) {
      u32 lo = (u32)f2bf(acc[m].x) | ((u32)f2bf(acc[m].y) << 16);
      u32 hi = (u32)f2bf(acc[m].z) | ((u32)f2bf(acc[m].w) << 16);
      *(uint2*)(ob + m * 512) = make_uint2(lo, hi);
    }
  } else {
    float* ob = outf + (size_t)b * (M * 512) + s * 4;
#pragma unroll
    for (int m = 0; m < M; m++) *(float4*)(ob + m * 512) = acc[m];
  }
}

extern "C" void kernel_launch(void* const* d_in, const int* in_sizes, int n_in,
                              void* d_out, int out_size, void* d_ws, size_t ws_size,
                              hipStream_t stream) {
  const float* x0   = (const float*)d_in[0];
  const float* W1_0 = (const float*)d_in[1];
  const float* b1_0 = (const float*)d_in[2];
  const float* W2_0 = (const float*)d_in[3];
  const float* b2_0 = (const float*)d_in[4];
  const float* Wg_0 = (const float*)d_in[5];
  const float* bg_0 = (const float*)d_in[6];
  const float* W1_1 = (const float*)d_in[7];
  const float* b1_1 = (const float*)d_in[8];
  const float* W2_1 = (const float*)d_in[9];
  const float* b2_1 = (const float*)d_in[10];
  const float* Wg_1 = (const float*)d_in[11];
  const float* bg_1 = (const float*)d_in[12];
  const float* sewt = (const float*)d_in[13];
  const float* sews = (const float*)d_in[14];
  float* out = (float*)d_out;

  char* p = (char*)d_ws;
  auto take = [&](size_t n) { char* r = p; p += (n + 255) & ~(size_t)255; return r; };
  u16*   x0bf = (u16*)take(4718592ull * 2);     // [B][9][512] bf16
  u16*   W1T0 = (u16*)take(9437184ull * 2);     // [18][1024][512] bf16
  u16*   W2T0 = (u16*)take(9437184ull * 2);     // [18][512][1024] bf16
  u16*   W1T1 = (u16*)take(9437184ull * 2);
  u16*   W2T1 = (u16*)take(9437184ull * 2);
  u16*   WgT0 = (u16*)take(82944ull * 2);       // [9][18][512] bf16
  u16*   WgT1 = (u16*)take(73728ull * 2);       // [8][18][512] bf16
  u16*   hbf  = (u16*)take(18874368ull * 2);    // [B][18][1024] bf16
  float* eo   = (float*)take(9437184ull * 4);   // [B][18][512] fp32
  u16*   x1bf = (u16*)take(4718592ull * 2);     // [B][9][512] bf16
  float* wsm0 = (float*)take(165888ull * 4);    // [B][9][18] fp32
  float* wsm1 = (float*)take(147456ull * 4);    // [B][8][18] fp32

  dim3 blk(256);
  // 1) prep split in two
  prep_w_kernel<<<dim3(9216), blk, 0, stream>>>(W1_0, W2_0, W1_1, W2_1,
                                                W1T0, W2T0, W1T1, W2T1);
  prep_misc_kernel<<<dim3(5220), blk, 0, stream>>>(Wg_0, Wg_1, WgT0, WgT1, x0, x0bf);
  // 2) layer0 GEMM1 + gating0. BM=256: 18 e x 4 mt x 8 nt = 576 blocks (nshift=5)
  gemm_fused_kernel<true, 9, 0, true><<<dim3(576 + 1152), blk, 0, stream>>>(
      x0bf, W1T0, b1_0, (void*)hbf, 4608, 1, 512, 18432, 1024, 1024, 512, 5, 576,
      WgT0, bg_0, sewt, sews, wsm0);
  // 3) layer0 GEMM2. 18 e x 4 mt x 4 nt = 288 blocks (nshift=4)
  gemm_fused_kernel<false, 9, 0, false><<<dim3(288), blk, 0, stream>>>(
      hbf, W2T0, b2_0, (void*)eo, 18432, 0, 1024, 9216, 512, 512, 1024, 4, 288,
      nullptr, nullptr, nullptr, nullptr, nullptr);
  // 4) layer0 combine -> x1 (bf16)
  wsum_kernel<9, true><<<dim3(512), blk, 0, stream>>>(eo, wsm0, nullptr, x1bf);
  // 5) layer1 GEMM1 + gating1
  gemm_fused_kernel<true, 8, 1, true><<<dim3(576 + 1024), blk, 0, stream>>>(
      x1bf, W1T1, b1_1, (void*)hbf, 4608, 1, 512, 18432, 1024, 1024, 512, 5, 576,
      WgT1, bg_1, sewt, sews, wsm1);
  // 6) layer1 GEMM2
  gemm_fused_kernel<false, 8, 1, false><<<dim3(288), blk, 0, stream>>>(
      hbf, W2T1, b2_1, (void*)eo, 18432, 0, 1024, 9216, 512, 512, 1024, 4, 288,
      nullptr, nullptr, nullptr, nullptr, nullptr);
  // 7) layer1 combine -> out (fp32)
  wsum_kernel<8, false><<<dim3(512), blk, 0, stream>>>(eo, wsm1, out, nullptr);
}

// Round 6
// 335.726 us; speedup vs baseline: 1.1198x; 1.1198x over previous
//
#include <hip/hip_runtime.h>

typedef unsigned short u16;
typedef unsigned int u32;
typedef __attribute__((ext_vector_type(8))) short short8;
typedef __attribute__((ext_vector_type(4))) float floatx4;

#define GLOAD_LDS16(gp, lp)                                                              \
  __builtin_amdgcn_global_load_lds((const __attribute__((address_space(1))) void*)(gp),  \
                                   (__attribute__((address_space(3))) void*)(lp), 16, 0, 0)

__device__ __forceinline__ u16 f2bf(float f) {
  u32 u = __float_as_uint(f);
  u += 0x7fffu + ((u >> 16) & 1u);   // round-to-nearest-even
  return (u16)(u >> 16);
}

__device__ __forceinline__ void bf8_to_f(const u16* p, float* o) {
  const uint4 v = *(const uint4*)p;
  const u32 a[4] = {v.x, v.y, v.z, v.w};
#pragma unroll
  for (int i = 0; i < 4; i++) {
    o[2 * i]     = __uint_as_float(a[i] << 16);
    o[2 * i + 1] = __uint_as_float(a[i] & 0xffff0000u);
  }
}

// ------ 64x64 transpose+cvt body (round-0 logic, single tensor) -----------------------
// id in [0,2304): e = id>>7, 128 tiles. mode 0: K=512,N=1024 (W1). mode 1: K=1024,N=512.
__device__ __forceinline__ void transpose_body(int id, const float* __restrict__ W,
                                               u16* __restrict__ WT, int mode,
                                               float* tile /* [64*65] */) {
  const int t = threadIdx.x;
  const int e = id >> 7;
  const int t128 = id & 127;
  const int K = mode ? 1024 : 512;
  const int N = mode ? 512 : 1024;
  const int kt = mode ? (t128 & 15) : (t128 & 7);
  const int nt = mode ? (t128 >> 4) : (t128 >> 3);
  const int k0 = kt * 64, n0 = nt * 64;

  const float* Wp = W + ((size_t)e * K + k0) * N + n0;
  const int r = t >> 4;          // 0..15
  const int c = (t & 15) << 2;   // 0..60
#pragma unroll
  for (int p = 0; p < 4; p++) {
    const int row = r + p * 16;
    const float4 v = *(const float4*)(Wp + (size_t)row * N + c);
    tile[row * 65 + c + 0] = v.x; tile[row * 65 + c + 1] = v.y;
    tile[row * 65 + c + 2] = v.z; tile[row * 65 + c + 3] = v.w;
  }
  __syncthreads();
  u16* WTp = WT + ((size_t)e * N + n0) * K + k0;
#pragma unroll
  for (int p = 0; p < 4; p++) {
    const int row = r + p * 16;  // n index within tile
    u32 lo = (u32)f2bf(tile[(c + 0) * 65 + row]) | ((u32)f2bf(tile[(c + 1) * 65 + row]) << 16);
    u32 hi = (u32)f2bf(tile[(c + 2) * 65 + row]) | ((u32)f2bf(tile[(c + 3) * 65 + row]) << 16);
    *(uint2*)(WTp + (size_t)row * K + c) = make_uint2(lo, hi);
  }
}

// ------ prep1: W1_0 transpose (2304) + Wg transpose (612) + x0 cvt (4608) -------------
__global__ __launch_bounds__(256) void prep1_kernel(
    const float* __restrict__ W1a, u16* __restrict__ T1a,
    const float* __restrict__ Wg0, const float* __restrict__ Wg1,
    u16* __restrict__ WgT0, u16* __restrict__ WgT1,
    const float* __restrict__ x0, u16* __restrict__ x0bf) {
  __shared__ float tile[64 * 65];
  const int id = blockIdx.x;
  const int t = threadIdx.x;
  if (id < 2304) {
    transpose_body(id, W1a, T1a, 0, tile);
  } else if (id < 2916) {
    int idx = (id - 2304) * 256 + t;
    const float* Wg = Wg0;
    u16* WgT = WgT0;
    if (idx >= 82944) { idx -= 82944; Wg = Wg1; WgT = WgT1; }
    const int d = idx & 511;
    const int r = idx >> 9;
    const int e = r % 18;
    const int m = r / 18;
    WgT[idx] = f2bf(Wg[((size_t)(m * 512 + d)) * 18 + e]);
  } else {
    const int i = (id - 2916) * 256 + t;   // 4608*256 == 1179648 float4s exactly
    const float4 v = ((const float4*)x0)[i];
    u32 lo = (u32)f2bf(v.x) | ((u32)f2bf(v.y) << 16);
    u32 hi = (u32)f2bf(v.z) | ((u32)f2bf(v.w) << 16);
    ((uint2*)x0bf)[i] = make_uint2(lo, hi);
  }
}

// ---------------- gating body: wsm[b][m][18] = softmax(x[b,m,:]·Wg[m] + bg[m]) + add --
// bid in [0, 128*M); wave handles 2 batches; x bf16 [B][9][512]; WgT bf16 [M][18][512]
template <int M, int LAYER>
__device__ __forceinline__ void gating_body(
    int bid, const u16* __restrict__ xbf, const u16* __restrict__ WgT,
    const float* __restrict__ bg, const float* __restrict__ sew_task,
    const float* __restrict__ sew_shared, float* __restrict__ wsm) {
  const int lane = threadIdx.x & 63;
  const int wave = threadIdx.x >> 6;
  const int m = bid >> 7;
  const int b0 = (bid & 127) * 8 + wave * 2;

  float xa[8], xb[8];
  bf8_to_f(xbf + (size_t)b0 * 4608 + m * 512 + lane * 8, xa);
  bf8_to_f(xbf + (size_t)(b0 + 1) * 4608 + m * 512 + lane * 8, xb);

  float lg0[18], lg1[18];
#pragma unroll
  for (int e = 0; e < 18; e++) {
    float w[8];
    bf8_to_f(WgT + ((size_t)m * 18 + e) * 512 + lane * 8, w);
    float s0 = 0.f, s1 = 0.f;
#pragma unroll
    for (int i = 0; i < 8; i++) { s0 = fmaf(w[i], xa[i], s0); s1 = fmaf(w[i], xb[i], s1); }
#pragma unroll
    for (int off = 1; off < 64; off <<= 1) {
      s0 += __shfl_xor(s0, off, 64);
      s1 += __shfl_xor(s1, off, 64);
    }
    const float bgv = bg[m * 18 + e];
    lg0[e] = s0 + bgv;
    lg1[e] = s1 + bgv;
  }
  float mx0 = lg0[0], mx1 = lg1[0];
#pragma unroll
  for (int e = 1; e < 18; e++) { mx0 = fmaxf(mx0, lg0[e]); mx1 = fmaxf(mx1, lg1[e]); }
  float sum0 = 0.f, sum1 = 0.f;
#pragma unroll
  for (int e = 0; e < 18; e++) { sum0 += __expf(lg0[e] - mx0); sum1 += __expf(lg1[e] - mx1); }
  float my0 = lg0[0], my1 = lg1[0];
#pragma unroll
  for (int e = 1; e < 18; e++)
    if (lane == e) { my0 = lg0[e]; my1 = lg1[e]; }
  float w0 = __expf(my0 - mx0) / sum0;
  float w1 = __expf(my1 - mx1) / sum1;
  if ((lane >> 1) == m) {
    float add;
    if (M == 9 && m == 8) add = sew_shared[lane & 1];
    else                  add = sew_task[m * 4 + 2 * LAYER + (lane & 1)];
    w0 += add; w1 += add;
  }
  if (lane < 18) {
    wsm[((size_t)b0 * M + m) * 18 + lane] = w0;
    wsm[((size_t)(b0 + 1) * M + m) * 18 + lane] = w1;
  }
}

// ---------------- MFMA GEMM (round-4 128^2 body) + gating tail + W-transpose tail ------
// grid: [0,G) GEMM (XCD-swizzled); [G, G+gate_cnt) gating; then 2304 transpose blocks.
template <bool RELU_BF16_OUT, int M, int LAYER, bool GATE, bool TRANS>
__global__ __launch_bounds__(256, 3) void gemm_fused_kernel(
    const u16* __restrict__ A, const u16* __restrict__ BT,
    const float* __restrict__ bias, void* __restrict__ Cout,
    int lda, int a_shift, int a_mul, int ldc, int c_mul, int N, int K, int nshift, int G,
    const u16* __restrict__ WgT, const float* __restrict__ bg,
    const float* __restrict__ sewt, const float* __restrict__ sews,
    float* __restrict__ wsm,
    int gate_cnt, const float* __restrict__ Wsrc, u16* __restrict__ Wdst, int wmode) {
  __shared__ __align__(16) u16 smem[16384];   // GEMM: As|Bs (32 KB); transpose: 64x65 f32
  if ((GATE || TRANS) && (int)blockIdx.x >= G) {
    const int rr = blockIdx.x - G;
    if (GATE && rr < gate_cnt) {
      gating_body<M, LAYER>(rr, A, WgT, bg, sewt, sews, wsm);
      return;
    }
    if (TRANS) transpose_body(rr - (GATE ? gate_cnt : 0), Wsrc, Wdst, wmode, (float*)smem);
    return;
  }
  u16* As = smem;
  u16* Bs = smem + 8192;

  const int tid = threadIdx.x;
  const int lane = tid & 63;
  const int wave = tid >> 6;

  const int L = blockIdx.x;
  const int per_xcd = G >> 3;
  const int g = (L & 7) * per_xcd + (L >> 3);
  const int e = g >> nshift;
  const int wb = g & ((1 << nshift) - 1);
  const int mt = wb & 7;           // M = 1024 always -> 8 row tiles (fastest: share B)
  const int nt = wb >> 3;
  const int m0 = mt << 7, n0 = nt << 7;

  const u16* Aexp = A + (size_t)((e >> a_shift) * a_mul);
  const u16* Bexp = BT + (size_t)e * (size_t)N * (size_t)K;

  // staging: chunk c (of 16) = 1KB = 8 rows; lane l -> row c*8 + l/8, swizzled col group
  const int colsw = (((lane & 7) ^ ((lane >> 3) & 7)) << 3);
  const u16* aptr[4];
  const u16* bptr[4];
  u16* lA[4];
  u16* lB[4];
#pragma unroll
  for (int i = 0; i < 4; i++) {
    const int cch = wave * 4 + i;
    const int row = cch * 8 + (lane >> 3);
    aptr[i] = Aexp + (size_t)(m0 + row) * lda + colsw;
    bptr[i] = Bexp + (size_t)(n0 + row) * K + colsw;
    lA[i] = As + cch * 512;
    lB[i] = Bs + cch * 512;
  }

  floatx4 acc[4][4];
#pragma unroll
  for (int i = 0; i < 4; i++)
#pragma unroll
    for (int j = 0; j < 4; j++) acc[i][j] = (floatx4){0.f, 0.f, 0.f, 0.f};

  const int wm = (wave & 1) << 6;
  const int wn = (wave >> 1) << 6;
  const int r15 = lane & 15;
  const int quad = lane >> 4;

  int aoff[4], boff[4];
#pragma unroll
  for (int i = 0; i < 4; i++) {
    const int ra = wm + i * 16 + r15;
    aoff[i] = ra * 64 + ((quad ^ (ra & 7)) << 3);
    const int rb = wn + i * 16 + r15;
    boff[i] = rb * 64 + ((quad ^ (rb & 7)) << 3);
  }

  for (int k0 = 0; k0 < K; k0 += 64) {
    __syncthreads();
#pragma unroll
    for (int i = 0; i < 4; i++) GLOAD_LDS16(aptr[i] + k0, lA[i]);
#pragma unroll
    for (int i = 0; i < 4; i++) GLOAD_LDS16(bptr[i] + k0, lB[i]);
    __syncthreads();
#pragma unroll
    for (int s = 0; s < 2; s++) {
      short8 af[4], bfr[4];
#pragma unroll
      for (int i = 0; i < 4; i++) af[i] = *(const short8*)(As + (aoff[i] ^ (s << 5)));
#pragma unroll
      for (int j = 0; j < 4; j++) bfr[j] = *(const short8*)(Bs + (boff[j] ^ (s << 5)));
      __builtin_amdgcn_s_setprio(1);
#pragma unroll
      for (int i = 0; i < 4; i++)
#pragma unroll
        for (int j = 0; j < 4; j++)
          acc[i][j] = __builtin_amdgcn_mfma_f32_16x16x32_bf16(af[i], bfr[j], acc[i][j], 0, 0, 0);
      __builtin_amdgcn_s_setprio(0);
    }
  }

  const int ccol0 = n0 + wn + r15;
  const int crow0 = m0 + wm + quad * 4;
  float bv[4];
#pragma unroll
  for (int j = 0; j < 4; j++) bv[j] = bias[e * N + ccol0 + j * 16];

  if constexpr (RELU_BF16_OUT) {
    u16* Co = (u16*)Cout + (size_t)e * c_mul;
#pragma unroll
    for (int i = 0; i < 4; i++)
#pragma unroll
      for (int r = 0; r < 4; r++) {
        const size_t rowoff = (size_t)(crow0 + i * 16 + r) * ldc;
#pragma unroll
        for (int j = 0; j < 4; j++) {
          float v = acc[i][j][r] + bv[j];
          v = v > 0.f ? v : 0.f;
          Co[rowoff + ccol0 + j * 16] = f2bf(v);
        }
      }
  } else {
    float* Co = (float*)Cout + (size_t)e * c_mul;
#pragma unroll
    for (int i = 0; i < 4; i++)
#pragma unroll
      for (int r = 0; r < 4; r++) {
        const size_t rowoff = (size_t)(crow0 + i * 16 + r) * ldc;
#pragma unroll
        for (int j = 0; j < 4; j++) Co[rowoff + ccol0 + j * 16] = acc[i][j][r] + bv[j];
      }
  }
}

// ---------------- weighted sum: out[b][m][:] = sum_e wsm[b][m][e] * eo[b][e][:] -------
template <int M, bool BF16OUT>
__global__ __launch_bounds__(256) void wsum_kernel(
    const float* __restrict__ eo, const float* __restrict__ wsm,
    float* __restrict__ outf, u16* __restrict__ outb) {
  __shared__ float ws[2 * M * 18];
  const int t = threadIdx.x;
  const int b0 = blockIdx.x * 2;
  for (int i = t; i < 2 * M * 18; i += 256) ws[i] = wsm[(size_t)b0 * M * 18 + i];
  __syncthreads();
  const int lb = t >> 7;
  const int s = t & 127;
  const int b = b0 + lb;
  const float* eob = eo + (size_t)b * 9216 + s * 4;
  const float* wr = ws + lb * M * 18;

  float4 acc[M];
#pragma unroll
  for (int m = 0; m < M; m++) acc[m] = make_float4(0.f, 0.f, 0.f, 0.f);
#pragma unroll
  for (int e = 0; e < 18; e++) {
    const float4 v = *(const float4*)(eob + e * 512);
#pragma unroll
    for (int m = 0; m < M; m++) {
      const float w = wr[m * 18 + e];
      acc[m].x = fmaf(w, v.x, acc[m].x);
      acc[m].y = fmaf(w, v.y, acc[m].y);
      acc[m].z = fmaf(w, v.z, acc[m].z);
      acc[m].w = fmaf(w, v.w, acc[m].w);
    }
  }
  if constexpr (BF16OUT) {
    u16* ob = outb + (size_t)b * 4608 + s * 4;
#pragma unroll
    for (int m = 0; m < M; m++) {
      u32 lo = (u32)f2bf(acc[m].x) | ((u32)f2bf(acc[m].y) << 16);
      u32 hi = (u32)f2bf(acc[m].z) | ((u32)f2bf(acc[m].w) << 16);
      *(uint2*)(ob + m * 512) = make_uint2(lo, hi);
    }
  } else {
    float* ob = outf + (size_t)b * (M * 512) + s * 4;
#pragma unroll
    for (int m = 0; m < M; m++) *(float4*)(ob + m * 512) = acc[m];
  }
}

extern "C" void kernel_launch(void* const* d_in, const int* in_sizes, int n_in,
                              void* d_out, int out_size, void* d_ws, size_t ws_size,
                              hipStream_t stream) {
  const float* x0   = (const float*)d_in[0];
  const float* W1_0 = (const float*)d_in[1];
  const float* b1_0 = (const float*)d_in[2];
  const float* W2_0 = (const float*)d_in[3];
  const float* b2_0 = (const float*)d_in[4];
  const float* Wg_0 = (const float*)d_in[5];
  const float* bg_0 = (const float*)d_in[6];
  const float* W1_1 = (const float*)d_in[7];
  const float* b1_1 = (const float*)d_in[8];
  const float* W2_1 = (const float*)d_in[9];
  const float* b2_1 = (const float*)d_in[10];
  const float* Wg_1 = (const float*)d_in[11];
  const float* bg_1 = (const float*)d_in[12];
  const float* sewt = (const float*)d_in[13];
  const float* sews = (const float*)d_in[14];
  float* out = (float*)d_out;

  char* p = (char*)d_ws;
  auto take = [&](size_t n) { char* r = p; p += (n + 255) & ~(size_t)255; return r; };
  u16*   x0bf = (u16*)take(4718592ull * 2);     // [B][9][512] bf16
  u16*   W1T0 = (u16*)take(9437184ull * 2);     // [18][1024][512] bf16
  u16*   W2T0 = (u16*)take(9437184ull * 2);     // [18][512][1024] bf16
  u16*   W1T1 = (u16*)take(9437184ull * 2);
  u16*   W2T1 = (u16*)take(9437184ull * 2);
  u16*   WgT0 = (u16*)take(82944ull * 2);       // [9][18][512] bf16
  u16*   WgT1 = (u16*)take(73728ull * 2);       // [8][18][512] bf16
  u16*   hbf  = (u16*)take(18874368ull * 2);    // [B][18][1024] bf16
  float* eo   = (float*)take(9437184ull * 4);   // [B][18][512] fp32
  u16*   x1bf = (u16*)take(4718592ull * 2);     // [B][9][512] bf16
  float* wsm0 = (float*)take(165888ull * 4);    // [B][9][18] fp32
  float* wsm1 = (float*)take(147456ull * 4);    // [B][8][18] fp32

  dim3 blk(256);
  // D1) prep: W1T0 transpose + Wg transposes + x0 cvt (everything GEMM1_0/gating0 needs)
  prep1_kernel<<<dim3(7524), blk, 0, stream>>>(W1_0, W1T0, Wg_0, Wg_1, WgT0, WgT1,
                                               x0, x0bf);
  // D2) layer0 GEMM1 + gating0 + fused W2_0 transpose (needed by D3)
  gemm_fused_kernel<true, 9, 0, true, true><<<dim3(1152 + 1152 + 2304), blk, 0, stream>>>(
      x0bf, W1T0, b1_0, (void*)hbf, 4608, 1, 512, 18432, 1024, 1024, 512, 6, 1152,
      WgT0, bg_0, sewt, sews, wsm0, 1152, W2_0, W2T0, 1);
  // D3) layer0 GEMM2 + fused W1_1 transpose (needed by D5)
  gemm_fused_kernel<false, 9, 0, false, true><<<dim3(576 + 2304), blk, 0, stream>>>(
      hbf, W2T0, b2_0, (void*)eo, 18432, 0, 1024, 9216, 512, 512, 1024, 5, 576,
      nullptr, nullptr, nullptr, nullptr, nullptr, 0, W1_1, W1T1, 0);
  // D4) layer0 combine -> x1 (bf16)
  wsum_kernel<9, true><<<dim3(512), blk, 0, stream>>>(eo, wsm0, nullptr, x1bf);
  // D5) layer1 GEMM1 + gating1 + fused W2_1 transpose (needed by D6)
  gemm_fused_kernel<true, 8, 1, true, true><<<dim3(1152 + 1024 + 2304), blk, 0, stream>>>(
      x1bf, W1T1, b1_1, (void*)hbf, 4608, 1, 512, 18432, 1024, 1024, 512, 6, 1152,
      WgT1, bg_1, sewt, sews, wsm1, 1024, W2_1, W2T1, 1);
  // D6) layer1 GEMM2
  gemm_fused_kernel<false, 8, 1, false, false><<<dim3(576), blk, 0, stream>>>(
      hbf, W2T1, b2_1, (void*)eo, 18432, 0, 1024, 9216, 512, 512, 1024, 5, 576,
      nullptr, nullptr, nullptr, nullptr, nullptr, 0, nullptr, nullptr, 0);
  // D7) layer1 combine -> out (fp32)
  wsum_kernel<8, false><<<dim3(512), blk, 0, stream>>>(eo, wsm1, out, nullptr);
}